// Round 1
// baseline (548.892 us; speedup 1.0000x reference)
//
#include <hip/hip_runtime.h>
#include <hip/hip_bf16.h>
#include <cstdint>
#include <cstddef>

typedef __attribute__((ext_vector_type(8))) __bf16 bf16x8;
typedef __attribute__((ext_vector_type(4))) __bf16 bf16x4;
typedef __attribute__((ext_vector_type(4))) float f32x4;

#define MFMA16(a, b, c) __builtin_amdgcn_mfma_f32_16x16x32_bf16(a, b, c, 0, 0, 0)

__device__ __forceinline__ void gload_lds16(const void* g, void* l) {
  __builtin_amdgcn_global_load_lds(
      (__attribute__((address_space(1))) uint32_t*)g,
      (__attribute__((address_space(3))) uint32_t*)l,
      16, 0, 0);
}

// ---------------- transpose + f32->bf16 convert: in [K][N] f32 -> out [N][K] bf16
__global__ __launch_bounds__(256) void transpose_cvt_kernel(
    const float* __restrict__ in, __bf16* __restrict__ out, int K, int N) {
  __shared__ float tile[32][33];
  int bx = blockIdx.x, by = blockIdx.y;
  int tx = threadIdx.x, ty = threadIdx.y;  // (32, 8)
  int gcol = bx * 32 + tx;
#pragma unroll
  for (int j = 0; j < 4; j++) {
    int grow = by * 32 + ty + j * 8;
    tile[ty + j * 8][tx] = in[(size_t)grow * N + gcol];
  }
  __syncthreads();
#pragma unroll
  for (int j = 0; j < 4; j++) {
    int n = bx * 32 + ty + j * 8;
    out[(size_t)n * K + by * 32 + tx] = (__bf16)tile[tx][ty + j * 8];
  }
}

// ---------------- LayerNorm: f32 [rows][1024] -> bf16, one block per row
__global__ __launch_bounds__(256) void ln_kernel(
    const float* __restrict__ x, const float* __restrict__ w,
    const float* __restrict__ b, __bf16* __restrict__ out) {
  int row = blockIdx.x;
  int t = threadIdx.x;
  const float4* xr = (const float4*)(x + (size_t)row * 1024);
  float4 v = xr[t];
  float s = v.x + v.y + v.z + v.w;
  float sq = v.x * v.x + v.y * v.y + v.z * v.z + v.w * v.w;
#pragma unroll
  for (int m = 1; m < 64; m <<= 1) {
    s += __shfl_xor(s, m);
    sq += __shfl_xor(sq, m);
  }
  __shared__ float rs[4], rq[4];
  int wid = t >> 6;
  if ((t & 63) == 0) { rs[wid] = s; rq[wid] = sq; }
  __syncthreads();
  s = rs[0] + rs[1] + rs[2] + rs[3];
  sq = rq[0] + rq[1] + rq[2] + rq[3];
  float mean = s * (1.0f / 1024.0f);
  float var = sq * (1.0f / 1024.0f) - mean * mean;
  float rstd = rsqrtf(var + 1e-5f);
  int c = t * 4;
  float4 wv = ((const float4*)w)[t];
  float4 bv = ((const float4*)b)[t];
  bf16x4 o;
  o[0] = (__bf16)((v.x - mean) * rstd * wv.x + bv.x);
  o[1] = (__bf16)((v.y - mean) * rstd * wv.y + bv.y);
  o[2] = (__bf16)((v.z - mean) * rstd * wv.z + bv.z);
  o[3] = (__bf16)((v.w - mean) * rstd * wv.w + bv.w);
  *(bf16x4*)(out + (size_t)row * 1024 + c) = o;
}

// ---------------- GEMM: C[M][N] = A[M][K] * W[K][N], W given transposed as BT[N][K]
// EPI 0: scatter to q/k/v bf16 buffers [3][16][4096][64]
// EPI 1: outf = resid + acc           (f32)
// EPI 2: outb = gelu(acc + bias)      (bf16)
// EPI 3: outf = resid + acc + bias    (f32)
template <int EPI>
__global__ __launch_bounds__(256, 2) void gemm_kernel(
    const __bf16* __restrict__ A, const __bf16* __restrict__ BT,
    int M, int N, int K,
    const float* __restrict__ resid, const float* __restrict__ bias,
    float* __restrict__ outf, __bf16* __restrict__ outb) {
  __shared__ __bf16 lsA[128 * 64];
  __shared__ __bf16 lsB[128 * 64];
  int t = threadIdx.x;
  int m0 = blockIdx.y * 128, n0 = blockIdx.x * 128;
  int wid = t >> 6, lane = t & 63, lo = lane & 15, g = lane >> 4;
  int wr = wid >> 1, wc = wid & 1;
  f32x4 acc[4][4] = {};
  const __bf16* ag = A + (size_t)(m0 + (t >> 3)) * K + (t & 7) * 8;
  const __bf16* bg = BT + (size_t)(n0 + (t >> 3)) * K + (t & 7) * 8;
  for (int k0 = 0; k0 < K; k0 += 64) {
#pragma unroll
    for (int i = 0; i < 4; i++) {
      gload_lds16(ag + (size_t)i * 32 * K + k0, &lsA[i * 2048 + t * 8]);
      gload_lds16(bg + (size_t)i * 32 * K + k0, &lsB[i * 2048 + t * 8]);
    }
    __syncthreads();
#pragma unroll
    for (int kk = 0; kk < 2; kk++) {
      bf16x8 af[4], bfr[4];
#pragma unroll
      for (int mi = 0; mi < 4; mi++)
        af[mi] = *(const bf16x8*)&lsA[(wr * 64 + mi * 16 + lo) * 64 + kk * 32 + g * 8];
#pragma unroll
      for (int ni = 0; ni < 4; ni++)
        bfr[ni] = *(const bf16x8*)&lsB[(wc * 64 + ni * 16 + lo) * 64 + kk * 32 + g * 8];
#pragma unroll
      for (int mi = 0; mi < 4; mi++)
#pragma unroll
        for (int ni = 0; ni < 4; ni++)
          acc[mi][ni] = MFMA16(af[mi], bfr[ni], acc[mi][ni]);
    }
    __syncthreads();
  }
#pragma unroll
  for (int mi = 0; mi < 4; mi++) {
#pragma unroll
    for (int ni = 0; ni < 4; ni++) {
      int col = n0 + wc * 64 + ni * 16 + lo;
#pragma unroll
      for (int r = 0; r < 4; r++) {
        int row = m0 + wr * 64 + mi * 16 + g * 4 + r;
        float val = acc[mi][ni][r];
        if (EPI == 0) {
          int sE = col >> 10, rem = col & 1023, hh = rem >> 6, d = rem & 63;
          outb[((size_t)(sE * 16 + hh) * 4096 + row) * 64 + d] = (__bf16)val;
        } else if (EPI == 1) {
          size_t idx = (size_t)row * N + col;
          outf[idx] = resid[idx] + val;
        } else if (EPI == 2) {
          float vv = val + bias[col];
          float gg = 0.5f * vv * (1.0f + erff(vv * 0.70710678118f));
          outb[(size_t)row * N + col] = (__bf16)gg;
        } else {
          size_t idx = (size_t)row * N + col;
          outf[idx] = resid[idx] + val + bias[col];
        }
      }
    }
  }
}

// ---------------- causal flash attention
// Q,K,V: [16][4096][64] bf16.  O: [4096][1024] bf16 (col = head*64 + d).
// Block: 64 q rows (4 waves x 16), KV tiles of 64.
__global__ __launch_bounds__(256, 2) void attn_kernel(
    const __bf16* __restrict__ Q, const __bf16* __restrict__ Kb,
    const __bf16* __restrict__ Vb, __bf16* __restrict__ O) {
  constexpr int NSEQ = 4096;
  int head = blockIdx.y;
  int qt = blockIdx.x;
  int t = threadIdx.x, wid = t >> 6, lane = t & 63, lo = lane & 15, g = lane >> 4;
  __shared__ __bf16 lk[64][72];
  __shared__ __bf16 lvt[64][72];
  __shared__ __bf16 lp[4][16][72];
  const __bf16* qh = Q + (size_t)head * NSEQ * 64;
  const __bf16* kh = Kb + (size_t)head * NSEQ * 64;
  const __bf16* vh = Vb + (size_t)head * NSEQ * 64;
  int qbase = qt * 64 + wid * 16;
  bf16x8 aq[2];
  aq[0] = *(const bf16x8*)&qh[(size_t)(qbase + lo) * 64 + g * 8];
  aq[1] = *(const bf16x8*)&qh[(size_t)(qbase + lo) * 64 + 32 + g * 8];
  f32x4 accO[4] = {};
  float mrow[4] = {-__builtin_inff(), -__builtin_inff(), -__builtin_inff(), -__builtin_inff()};
  float lrow[4] = {0.f, 0.f, 0.f, 0.f};
  const float scale = 0.125f;
  for (int kt = 0; kt <= qt; kt++) {
    // stage K tile [64][64] row-major (padded) and V tile transposed [d][key]
#pragma unroll
    for (int i = 0; i < 2; i++) {
      int c = t + i * 256;
      int krow = c >> 3, c8 = c & 7;
      uint4 kv = *(const uint4*)&kh[((size_t)kt * 64 + krow) * 64 + c8 * 8];
      *(uint4*)&lk[krow][c8 * 8] = kv;
      uint4 vv = *(const uint4*)&vh[((size_t)kt * 64 + krow) * 64 + c8 * 8];
      const __bf16* vp = (const __bf16*)&vv;
#pragma unroll
      for (int j = 0; j < 8; j++) lvt[c8 * 8 + j][krow] = vp[j];
    }
    __syncthreads();
    // S = Q K^T (16 q x 64 keys per wave)
    float sv[4][4];
#pragma unroll
    for (int kc = 0; kc < 4; kc++) {
      f32x4 s = {};
#pragma unroll
      for (int kk = 0; kk < 2; kk++) {
        bf16x8 bk = *(const bf16x8*)&lk[kc * 16 + lo][kk * 32 + g * 8];
        s = MFMA16(aq[kk], bk, s);
      }
#pragma unroll
      for (int r = 0; r < 4; r++) {
        float xv = s[r] * scale;
        if (kt == qt) {
          int key = kt * 64 + kc * 16 + lo;
          int qi = qbase + g * 4 + r;
          if (key > qi) xv = -__builtin_inff();
        }
        sv[kc][r] = xv;
      }
    }
    // online softmax
#pragma unroll
    for (int r = 0; r < 4; r++) {
      float mt = fmaxf(fmaxf(sv[0][r], sv[1][r]), fmaxf(sv[2][r], sv[3][r]));
#pragma unroll
      for (int m = 1; m < 16; m <<= 1) mt = fmaxf(mt, __shfl_xor(mt, m));
      float mn = fmaxf(mrow[r], mt);
      float alpha = __expf(mrow[r] - mn);
      mrow[r] = mn;
      float psum = 0.f;
#pragma unroll
      for (int kc = 0; kc < 4; kc++) {
        float p = __expf(sv[kc][r] - mn);
        psum += p;
        lp[wid][g * 4 + r][kc * 16 + lo] = (__bf16)p;
      }
#pragma unroll
      for (int m = 1; m < 16; m <<= 1) psum += __shfl_xor(psum, m);
      lrow[r] = lrow[r] * alpha + psum;
#pragma unroll
      for (int dc = 0; dc < 4; dc++) accO[dc][r] *= alpha;
    }
    // O += P V
#pragma unroll
    for (int kk = 0; kk < 2; kk++) {
      bf16x8 ap = *(const bf16x8*)&lp[wid][lo][kk * 32 + g * 8];
#pragma unroll
      for (int dc = 0; dc < 4; dc++) {
        bf16x8 bv = *(const bf16x8*)&lvt[dc * 16 + lo][kk * 32 + g * 8];
        accO[dc] = MFMA16(ap, bv, accO[dc]);
      }
    }
    __syncthreads();
  }
#pragma unroll
  for (int dc = 0; dc < 4; dc++) {
#pragma unroll
    for (int r = 0; r < 4; r++) {
      int qi = qbase + g * 4 + r;
      float val = accO[dc][r] / lrow[r];
      O[(size_t)qi * 1024 + head * 64 + dc * 16 + lo] = (__bf16)val;
    }
  }
}

extern "C" void kernel_launch(void* const* d_in, const int* in_sizes, int n_in,
                              void* d_out, int out_size, void* d_ws, size_t ws_size,
                              hipStream_t stream) {
  const float* x = (const float*)d_in[0];
  const float* ln1_w = (const float*)d_in[1];
  const float* ln1_b = (const float*)d_in[2];
  const float* ln2_w = (const float*)d_in[3];
  const float* ln2_b = (const float*)d_in[4];
  const float* w_qkv = (const float*)d_in[5];  // [1024][3072]
  const float* w_o = (const float*)d_in[6];    // [1024][1024]
  const float* w_ff1 = (const float*)d_in[7];  // [1024][4096]
  const float* b_ff1 = (const float*)d_in[8];
  const float* w_ff2 = (const float*)d_in[9];  // [4096][1024]
  const float* b_ff2 = (const float*)d_in[10];
  float* out = (float*)d_out;

  const size_t D = 1024, NT = 4096;
  __bf16* wqkvT = (__bf16*)d_ws;                 // 3072*1024
  __bf16* woT = wqkvT + 3072 * D;                // 1024*1024
  __bf16* wff1T = woT + D * D;                   // 4096*1024
  __bf16* wff2T = wff1T + 4096 * D;              // 1024*4096
  __bf16* hbuf = wff2T + D * 4096;               // 4096*1024 (h, then h2)
  __bf16* qkvb = hbuf + NT * D;                  // 3*16*4096*64
  __bf16* attnb = qkvb + 3 * NT * D;             // 4096*1024
  __bf16* a1 = qkvb;                             // 4096*4096, overlaps dead qkv+attn
  float* x2 = (float*)(attnb + NT * D);          // 4096*1024 f32

  dim3 tb(32, 8);
  // weight transposes (f32 [K][N] -> bf16 [N][K])
  transpose_cvt_kernel<<<dim3(3072 / 32, 1024 / 32), tb, 0, stream>>>(w_qkv, wqkvT, 1024, 3072);
  transpose_cvt_kernel<<<dim3(1024 / 32, 1024 / 32), tb, 0, stream>>>(w_o, woT, 1024, 1024);
  transpose_cvt_kernel<<<dim3(4096 / 32, 1024 / 32), tb, 0, stream>>>(w_ff1, wff1T, 1024, 4096);
  transpose_cvt_kernel<<<dim3(1024 / 32, 4096 / 32), tb, 0, stream>>>(w_ff2, wff2T, 4096, 1024);

  // h = LN1(x)
  ln_kernel<<<4096, 256, 0, stream>>>(x, ln1_w, ln1_b, hbuf);
  // qkv = h @ w_qkv  (scatter to q/k/v)
  gemm_kernel<0><<<dim3(3072 / 128, 4096 / 128), 256, 0, stream>>>(
      hbuf, wqkvT, 4096, 3072, 1024, nullptr, nullptr, nullptr, qkvb);
  // attention
  attn_kernel<<<dim3(64, 16), 256, 0, stream>>>(
      qkvb, qkvb + 16 * NT * 64, qkvb + 32 * NT * 64, attnb);
  // x2 = x + attn @ w_o
  gemm_kernel<1><<<dim3(1024 / 128, 4096 / 128), 256, 0, stream>>>(
      attnb, woT, 4096, 1024, 1024, x, nullptr, x2, nullptr);
  // h2 = LN2(x2)
  ln_kernel<<<4096, 256, 0, stream>>>(x2, ln2_w, ln2_b, hbuf);
  // a1 = gelu(h2 @ w_ff1 + b_ff1)
  gemm_kernel<2><<<dim3(4096 / 128, 4096 / 128), 256, 0, stream>>>(
      hbuf, wff1T, 4096, 4096, 1024, nullptr, b_ff1, nullptr, a1);
  // out = x2 + a1 @ w_ff2 + b_ff2
  gemm_kernel<3><<<dim3(1024 / 128, 4096 / 128), 256, 0, stream>>>(
      a1, wff2T, 4096, 1024, 4096, x2, b_ff2, out, nullptr);
}

// Round 2
// 386.156 us; speedup vs baseline: 1.4214x; 1.4214x over previous
//
#include <hip/hip_runtime.h>
#include <hip/hip_bf16.h>
#include <cstdint>
#include <cstddef>

typedef __attribute__((ext_vector_type(8))) __bf16 bf16x8;
typedef __attribute__((ext_vector_type(4))) __bf16 bf16x4;
typedef __attribute__((ext_vector_type(4))) float f32x4;
typedef __attribute__((ext_vector_type(16))) float f32x16;
typedef __attribute__((ext_vector_type(4))) unsigned int uint4v;

#define MFMA16(a, b, c) __builtin_amdgcn_mfma_f32_16x16x32_bf16(a, b, c, 0, 0, 0)
#define MFMA32(a, b, c) __builtin_amdgcn_mfma_f32_32x32x16_bf16(a, b, c, 0, 0, 0)

__device__ __forceinline__ void gload_lds16(const void* g, void* l) {
  __builtin_amdgcn_global_load_lds(
      (__attribute__((address_space(1))) uint32_t*)g,
      (__attribute__((address_space(3))) uint32_t*)l,
      16, 0, 0);
}

__device__ __forceinline__ unsigned pkbf(float a, float b) {
  unsigned short x = __builtin_bit_cast(unsigned short, (__bf16)a);
  unsigned short y = __builtin_bit_cast(unsigned short, (__bf16)b);
  return (unsigned)x | ((unsigned)y << 16);
}

// ---------------- transpose + f32->bf16 convert: in [K][N] f32 -> out [N][K] bf16
__global__ __launch_bounds__(256) void transpose_cvt_kernel(
    const float* __restrict__ in, __bf16* __restrict__ out, int K, int N) {
  __shared__ float tile[32][33];
  int bx = blockIdx.x, by = blockIdx.y;
  int tx = threadIdx.x, ty = threadIdx.y;  // (32, 8)
  int gcol = bx * 32 + tx;
#pragma unroll
  for (int j = 0; j < 4; j++) {
    int grow = by * 32 + ty + j * 8;
    tile[ty + j * 8][tx] = in[(size_t)grow * N + gcol];
  }
  __syncthreads();
#pragma unroll
  for (int j = 0; j < 4; j++) {
    int n = bx * 32 + ty + j * 8;
    out[(size_t)n * K + by * 32 + tx] = (__bf16)tile[tx][ty + j * 8];
  }
}

// ---------------- LayerNorm: f32 [rows][1024] -> bf16, one block per row
__global__ __launch_bounds__(256) void ln_kernel(
    const float* __restrict__ x, const float* __restrict__ w,
    const float* __restrict__ b, __bf16* __restrict__ out) {
  int row = blockIdx.x;
  int t = threadIdx.x;
  const float4* xr = (const float4*)(x + (size_t)row * 1024);
  float4 v = xr[t];
  float s = v.x + v.y + v.z + v.w;
  float sq = v.x * v.x + v.y * v.y + v.z * v.z + v.w * v.w;
#pragma unroll
  for (int m = 1; m < 64; m <<= 1) {
    s += __shfl_xor(s, m);
    sq += __shfl_xor(sq, m);
  }
  __shared__ float rs[4], rq[4];
  int wid = t >> 6;
  if ((t & 63) == 0) { rs[wid] = s; rq[wid] = sq; }
  __syncthreads();
  s = rs[0] + rs[1] + rs[2] + rs[3];
  sq = rq[0] + rq[1] + rq[2] + rq[3];
  float mean = s * (1.0f / 1024.0f);
  float var = sq * (1.0f / 1024.0f) - mean * mean;
  float rstd = rsqrtf(var + 1e-5f);
  int c = t * 4;
  float4 wv = ((const float4*)w)[t];
  float4 bv = ((const float4*)b)[t];
  bf16x4 o;
  o[0] = (__bf16)((v.x - mean) * rstd * wv.x + bv.x);
  o[1] = (__bf16)((v.y - mean) * rstd * wv.y + bv.y);
  o[2] = (__bf16)((v.z - mean) * rstd * wv.z + bv.z);
  o[3] = (__bf16)((v.w - mean) * rstd * wv.w + bv.w);
  *(bf16x4*)(out + (size_t)row * 1024 + c) = o;
}

// ---------------- GEMM: C[M][N] = A[M][K] * W[K][N], W given transposed as BT[N][K]
// EPI 0: scatter q,k to [2][16][4096][64], v TRANSPOSED to [16][64][4096]
// EPI 1: outf = resid + acc           (f32)
// EPI 2: outb = gelu(acc + bias)      (bf16)
// EPI 3: outf = resid + acc + bias    (f32)
template <int EPI>
__global__ __launch_bounds__(256, 2) void gemm_kernel(
    const __bf16* __restrict__ A, const __bf16* __restrict__ BT,
    int M, int N, int K,
    const float* __restrict__ resid, const float* __restrict__ bias,
    float* __restrict__ outf, __bf16* __restrict__ outb) {
  __shared__ __bf16 lsA[128 * 64];
  __shared__ __bf16 lsB[128 * 64];
  int t = threadIdx.x;
  int m0 = blockIdx.y * 128, n0 = blockIdx.x * 128;
  int wid = t >> 6, lane = t & 63, lo = lane & 15, g = lane >> 4;
  int wr = wid >> 1, wc = wid & 1;
  f32x4 acc[4][4] = {};
  const __bf16* ag = A + (size_t)(m0 + (t >> 3)) * K + (t & 7) * 8;
  const __bf16* bg = BT + (size_t)(n0 + (t >> 3)) * K + (t & 7) * 8;
  for (int k0 = 0; k0 < K; k0 += 64) {
#pragma unroll
    for (int i = 0; i < 4; i++) {
      gload_lds16(ag + (size_t)i * 32 * K + k0, &lsA[i * 2048 + t * 8]);
      gload_lds16(bg + (size_t)i * 32 * K + k0, &lsB[i * 2048 + t * 8]);
    }
    __syncthreads();
#pragma unroll
    for (int kk = 0; kk < 2; kk++) {
      bf16x8 af[4], bfr[4];
#pragma unroll
      for (int mi = 0; mi < 4; mi++)
        af[mi] = *(const bf16x8*)&lsA[(wr * 64 + mi * 16 + lo) * 64 + kk * 32 + g * 8];
#pragma unroll
      for (int ni = 0; ni < 4; ni++)
        bfr[ni] = *(const bf16x8*)&lsB[(wc * 64 + ni * 16 + lo) * 64 + kk * 32 + g * 8];
#pragma unroll
      for (int mi = 0; mi < 4; mi++)
#pragma unroll
        for (int ni = 0; ni < 4; ni++)
          acc[mi][ni] = MFMA16(af[mi], bfr[ni], acc[mi][ni]);
    }
    __syncthreads();
  }
#pragma unroll
  for (int mi = 0; mi < 4; mi++) {
#pragma unroll
    for (int ni = 0; ni < 4; ni++) {
      int col = n0 + wc * 64 + ni * 16 + lo;
      int row0 = m0 + wr * 64 + mi * 16 + g * 4;
      if (EPI == 0) {
        int sE = col >> 10, rem = col & 1023, hh = rem >> 6, d = rem & 63;
        if (sE < 2) {
#pragma unroll
          for (int r = 0; r < 4; r++)
            outb[((size_t)(sE * 16 + hh) * 4096 + row0 + r) * 64 + d] = (__bf16)acc[mi][ni][r];
        } else {
          bf16x4 pk4;
#pragma unroll
          for (int r = 0; r < 4; r++) pk4[r] = (__bf16)acc[mi][ni][r];
          *(bf16x4*)&outb[(size_t)32 * 4096 * 64 + ((size_t)(hh * 64 + d)) * 4096 + row0] = pk4;
        }
      } else {
#pragma unroll
        for (int r = 0; r < 4; r++) {
          int row = row0 + r;
          float val = acc[mi][ni][r];
          if (EPI == 1) {
            size_t idx = (size_t)row * N + col;
            outf[idx] = resid[idx] + val;
          } else if (EPI == 2) {
            float vv = val + bias[col];
            float gg = 0.5f * vv * (1.0f + erff(vv * 0.70710678118f));
            outb[(size_t)row * N + col] = (__bf16)gg;
          } else {
            size_t idx = (size_t)row * N + col;
            outf[idx] = resid[idx] + val + bias[col];
          }
        }
      }
    }
  }
}

// ---------------- causal flash attention, swapped-QK^T 32x32 structure
// Q,K: [16][4096][64] bf16. VT: [16][64][4096] bf16. O: [4096][1024] bf16.
// Block: 128 q rows (4 waves x 32), KV tiles of 64, double-buffered LDS.
__global__ __launch_bounds__(256, 2) void attn_kernel(
    const __bf16* __restrict__ Q, const __bf16* __restrict__ Kb,
    const __bf16* __restrict__ VTb, __bf16* __restrict__ O) {
  constexpr int NSEQ = 4096;
  __shared__ __bf16 lds[2][2][64 * 64];  // [buf][K / VT][64 rows x 64 elems], 32 KiB
  int head = blockIdx.y;
  int qt = (int)gridDim.x - 1 - (int)blockIdx.x;  // big blocks dispatch first
  int t = threadIdx.x, wid = t >> 6, lane = t & 63;
  int lo = lane & 31, hi = lane >> 5;
  const __bf16* kh = Kb + (size_t)head * NSEQ * 64;
  const __bf16* vth = VTb + (size_t)head * 64 * NSEQ;
  int qbase = qt * 128 + wid * 32;
  int qrow = qbase + lo;
  const __bf16* qh = Q + (size_t)head * NSEQ * 64 + (size_t)qrow * 64;
  bf16x8 bq[4];
#pragma unroll
  for (int c = 0; c < 4; c++) bq[c] = *(const bf16x8*)(qh + c * 16 + hi * 8);

  f32x16 acc0 = {}, acc1 = {};  // O^T: d rows lo and 32+lo, col = q = lo
  float m2 = -3.0e38f, l = 0.f;
  int lastk = qbase >> 6;       // the (single) diagonal tile for this wave
  int ntiles = 2 * qt + 2;

  auto stage = [&](int buf, int kt) {
#pragma unroll
    for (int i = 0; i < 2; i++) {
      int idx = i * 256 + t;           // 0..511
      int row = idx >> 3, g = idx & 7;
      int gs = g ^ (row & 7);          // source-side swizzle (linear LDS dest)
      gload_lds16(kh + ((size_t)(0 + row)) * 64 + (size_t)kt * 64 * 64 + gs * 8,
                  &lds[buf][0][idx * 8]);
      gload_lds16(vth + (size_t)row * NSEQ + kt * 64 + gs * 8,
                  &lds[buf][1][idx * 8]);
    }
  };

  stage(0, 0);
  __syncthreads();
  for (int kt = 0; kt < ntiles; kt++) {
    int cur = kt & 1;
    if (kt + 1 < ntiles) stage(cur ^ 1, kt + 1);
    if (kt <= lastk) {
      const __bf16* lk = lds[cur][0];
      const __bf16* lvt = lds[cur][1];
      // S^T = K . Q^T  (lane: col = q = lo, 32 of 64 keys)
      f32x16 s0 = {}, s1 = {};
#pragma unroll
      for (int c = 0; c < 4; c++) {
        bf16x8 ka0 = *(const bf16x8*)&lk[(size_t)lo * 64 + (((c * 2 + hi) ^ (lo & 7)) * 8)];
        bf16x8 ka1 = *(const bf16x8*)&lk[(size_t)(32 + lo) * 64 + (((c * 2 + hi) ^ (lo & 7)) * 8)];
        s0 = MFMA32(ka0, bq[c], s0);
        s1 = MFMA32(ka1, bq[c], s1);
      }
      const float SC = 0.125f * 1.44269504088896f;  // scale * log2(e)
      float sv[32];
#pragma unroll
      for (int i = 0; i < 16; i++) { sv[i] = s0[i] * SC; sv[16 + i] = s1[i] * SC; }
      if (kt == lastk) {
#pragma unroll
        for (int i = 0; i < 32; i++) {
          int r = i & 15, kc = i >> 4;
          int key = kt * 64 + kc * 32 + (r & 3) + 8 * (r >> 2) + 4 * hi;
          if (key > qrow) sv[i] = -3.0e38f;
        }
      }
      float mloc = sv[0];
#pragma unroll
      for (int i = 1; i < 32; i++) mloc = fmaxf(mloc, sv[i]);
      mloc = fmaxf(mloc, __shfl_xor(mloc, 32));
      float mn = fmaxf(m2, mloc);
      float alpha = exp2f(m2 - mn);
      m2 = mn;
      float ps0 = 0, ps1 = 0, ps2 = 0, ps3 = 0;
#pragma unroll
      for (int i = 0; i < 32; i += 4) {
        sv[i] = exp2f(sv[i] - mn);       ps0 += sv[i];
        sv[i + 1] = exp2f(sv[i + 1] - mn); ps1 += sv[i + 1];
        sv[i + 2] = exp2f(sv[i + 2] - mn); ps2 += sv[i + 2];
        sv[i + 3] = exp2f(sv[i + 3] - mn); ps3 += sv[i + 3];
      }
      float ps = (ps0 + ps1) + (ps2 + ps3);
      ps += __shfl_xor(ps, 32);
      l = l * alpha + ps;
#pragma unroll
      for (int i = 0; i < 16; i++) { acc0[i] *= alpha; acc1[i] *= alpha; }
      // pack P (bf16) and redistribute halves (emulated permlane32_swap)
      uint4v pw[4];
#pragma unroll
      for (int b = 0; b < 4; b++) {
        int off = b * 8;
        unsigned w0 = pkbf(sv[off + 0], sv[off + 1]);
        unsigned w1 = pkbf(sv[off + 2], sv[off + 3]);
        unsigned w2 = pkbf(sv[off + 4], sv[off + 5]);
        unsigned w3 = pkbf(sv[off + 6], sv[off + 7]);
        unsigned t0 = __shfl_xor(w0, 32), t1 = __shfl_xor(w1, 32);
        unsigned t2 = __shfl_xor(w2, 32), t3 = __shfl_xor(w3, 32);
        pw[b][0] = hi ? t2 : w0;
        pw[b][1] = hi ? t3 : w1;
        pw[b][2] = hi ? w2 : t0;
        pw[b][3] = hi ? w3 : t1;
      }
      // O^T += V^T . P^T
#pragma unroll
      for (int b = 0; b < 4; b++) {
        bf16x8 pf = __builtin_bit_cast(bf16x8, pw[b]);
        bf16x8 va0 = *(const bf16x8*)&lvt[(size_t)lo * 64 + (((b * 2 + hi) ^ (lo & 7)) * 8)];
        bf16x8 va1 = *(const bf16x8*)&lvt[(size_t)(32 + lo) * 64 + (((b * 2 + hi) ^ (lo & 7)) * 8)];
        acc0 = MFMA32(va0, pf, acc0);
        acc1 = MFMA32(va1, pf, acc1);
      }
    }
    __syncthreads();
  }
  // epilogue: normalize, bounce through (now free) LDS, coalesced store
  float invl = 1.0f / l;
  __bf16* region = ((__bf16*)lds) + wid * 2048;  // per-wave 32 rows x 64 elems
#pragma unroll
  for (int dt = 0; dt < 2; dt++) {
#pragma unroll
    for (int rp = 0; rp < 8; rp++) {
      int r = rp * 2;
      float e0 = (dt ? acc1[r] : acc0[r]) * invl;
      float e1 = (dt ? acc1[r + 1] : acc0[r + 1]) * invl;
      int d = dt * 32 + (r & 3) + 8 * (r >> 2) + 4 * hi;
      int bytecol = d * 2;
      int g16 = bytecol >> 4, rem16 = bytecol & 15;
      *(unsigned*)((char*)region + lo * 128 + ((g16 ^ (lo & 7)) * 16 + rem16)) = pkbf(e0, e1);
    }
  }
  int qg0 = qt * 128 + wid * 32;
#pragma unroll
  for (int j = 0; j < 4; j++) {
    int idx = j * 64 + lane;
    int row = idx >> 3, g = idx & 7;
    bf16x8 v = *(const bf16x8*)((char*)region + row * 128 + ((g ^ (row & 7)) * 16));
    *(bf16x8*)&O[(size_t)(qg0 + row) * 1024 + head * 64 + g * 8] = v;
  }
}

extern "C" void kernel_launch(void* const* d_in, const int* in_sizes, int n_in,
                              void* d_out, int out_size, void* d_ws, size_t ws_size,
                              hipStream_t stream) {
  const float* x = (const float*)d_in[0];
  const float* ln1_w = (const float*)d_in[1];
  const float* ln1_b = (const float*)d_in[2];
  const float* ln2_w = (const float*)d_in[3];
  const float* ln2_b = (const float*)d_in[4];
  const float* w_qkv = (const float*)d_in[5];  // [1024][3072]
  const float* w_o = (const float*)d_in[6];    // [1024][1024]
  const float* w_ff1 = (const float*)d_in[7];  // [1024][4096]
  const float* b_ff1 = (const float*)d_in[8];
  const float* w_ff2 = (const float*)d_in[9];  // [4096][1024]
  const float* b_ff2 = (const float*)d_in[10];
  float* out = (float*)d_out;

  const size_t D = 1024, NT = 4096;
  __bf16* wqkvT = (__bf16*)d_ws;                 // 3072*1024
  __bf16* woT = wqkvT + 3072 * D;                // 1024*1024
  __bf16* wff1T = woT + D * D;                   // 4096*1024
  __bf16* wff2T = wff1T + 4096 * D;              // 1024*4096
  __bf16* hbuf = wff2T + D * 4096;               // 4096*1024 (h, then h2)
  __bf16* qkvb = hbuf + NT * D;                  // q,k [2][16][4096][64] + vT [16][64][4096]
  __bf16* attnb = qkvb + 3 * NT * D;             // 4096*1024
  __bf16* a1 = qkvb;                             // 4096*4096, overlaps dead qkv+attn
  float* x2 = (float*)(attnb + NT * D);          // 4096*1024 f32

  dim3 tb(32, 8);
  transpose_cvt_kernel<<<dim3(3072 / 32, 1024 / 32), tb, 0, stream>>>(w_qkv, wqkvT, 1024, 3072);
  transpose_cvt_kernel<<<dim3(1024 / 32, 1024 / 32), tb, 0, stream>>>(w_o, woT, 1024, 1024);
  transpose_cvt_kernel<<<dim3(4096 / 32, 1024 / 32), tb, 0, stream>>>(w_ff1, wff1T, 1024, 4096);
  transpose_cvt_kernel<<<dim3(1024 / 32, 4096 / 32), tb, 0, stream>>>(w_ff2, wff2T, 4096, 1024);

  ln_kernel<<<4096, 256, 0, stream>>>(x, ln1_w, ln1_b, hbuf);
  gemm_kernel<0><<<dim3(3072 / 128, 4096 / 128), 256, 0, stream>>>(
      hbuf, wqkvT, 4096, 3072, 1024, nullptr, nullptr, nullptr, qkvb);
  attn_kernel<<<dim3(32, 16), 256, 0, stream>>>(
      qkvb, qkvb + 16 * NT * 64, qkvb + 32 * NT * 64, attnb);
  gemm_kernel<1><<<dim3(1024 / 128, 4096 / 128), 256, 0, stream>>>(
      attnb, woT, 4096, 1024, 1024, x, nullptr, x2, nullptr);
  ln_kernel<<<4096, 256, 0, stream>>>(x2, ln2_w, ln2_b, hbuf);
  gemm_kernel<2><<<dim3(4096 / 128, 4096 / 128), 256, 0, stream>>>(
      hbuf, wff1T, 4096, 4096, 1024, nullptr, b_ff1, nullptr, a1);
  gemm_kernel<3><<<dim3(1024 / 128, 4096 / 128), 256, 0, stream>>>(
      a1, wff2T, 4096, 1024, 4096, x2, b_ff2, out, nullptr);
}